// Round 13
// baseline (238.903 us; speedup 1.0000x reference)
//
#include <hip/hip_runtime.h>
#include <hip/hip_bf16.h>
#include <stdint.h>

#define S_LEN 2048
#define NH 16
#define NB_DELTA (2*S_LEN-1)   // 4095
#define LOG2E 1.4426950408889634f

typedef __attribute__((ext_vector_type(8))) __bf16 bf16x8;
typedef __attribute__((ext_vector_type(4))) float f32x4;

__device__ __forceinline__ unsigned short f2bf(float f){   // RNE
    union { float f; unsigned int u; } v; v.f = f;
    unsigned int u = v.u;
    return (unsigned short)((u + 0x7FFFu + ((u >> 16) & 1u)) >> 16);
}
__device__ __forceinline__ float bf2f(unsigned short u){
    union { unsigned int u; float f; } v; v.u = ((unsigned int)u) << 16;
    return v.f;
}
__device__ __forceinline__ unsigned int pkbf(float a, float b){   // HW packed cvt (RNE)
    __hip_bfloat162 h = __float22bfloat162_rn(float2{a, b});
    unsigned int u;
    __builtin_memcpy(&u, &h, 4);
    return u;
}
#if __has_builtin(__builtin_amdgcn_exp2f)
__device__ __forceinline__ float fexp2(float x){ return __builtin_amdgcn_exp2f(x); }
#else
__device__ __forceinline__ float fexp2(float x){ return __expf(x * 0.69314718056f); }
#endif

// async global->LDS, 16B per lane; LDS dest = wave-uniform base + lane*16
__device__ __forceinline__ void gload16(const void* g, void* l){
    __builtin_amdgcn_global_load_lds(
        (const __attribute__((address_space(1))) void*)(uintptr_t)g,
        (__attribute__((address_space(3))) void*)(uintptr_t)l, 16, 0, 0);
}

// ---------------- fused prep (v1 -- measured best): z<4 -> transpose+cast W[z];
// z==4 -> hs cast + bias table. biasT is PRE-SCALED: (bias - 16) * log2e.
__global__ __launch_bounds__(256) void prep_kernel(
    const float* __restrict__ hs, unsigned short* __restrict__ hsb,
    const float* __restrict__ W0, const float* __restrict__ W1,
    const float* __restrict__ W2, const float* __restrict__ W3,
    unsigned short* __restrict__ D0, unsigned short* __restrict__ D1,
    unsigned short* __restrict__ D2, unsigned short* __restrict__ D3,
    const float* __restrict__ rel_bias, float* __restrict__ biasT){
    if (blockIdx.z == 4) {
        int bi = blockIdx.y * 32 + blockIdx.x;   // 0..1023
        for (int it = 0; it < 4; it++) {
            int i = bi * 4096 + it * 1024 + threadIdx.x * 4;
            float4 f = *(const float4*)(hs + i);
            ushort4 o;
            o.x = f2bf(f.x); o.y = f2bf(f.y); o.z = f2bf(f.z); o.w = f2bf(f.w);
            *(ushort4*)(hsb + i) = o;
        }
        if (bi < 16) {
            int t = bi * 256 + threadIdx.x;
            if (t < NB_DELTA) {
                int delta = t - (S_LEN - 1);          // j - i
                int bucket = (delta > 0) ? 16 : 0;
                int a = delta < 0 ? -delta : delta;
                int b;
                if (a < 8) b = a;
                else {
                    int bl = 33 - __builtin_clz(a * a);   // 8 + floor(2*log2(a/8)), exact
                    b = bl < 15 ? bl : 15;
                }
                bucket += b;
                for (int h = 0; h < NH; h++)
                    biasT[h * NB_DELTA + t] = (rel_bias[bucket * NH + h] - 16.f) * LOG2E;
            }
        }
        return;
    }
    const float* src; unsigned short* dst;
    switch (blockIdx.z) {
        case 0: src = W0; dst = D0; break;
        case 1: src = W1; dst = D1; break;
        case 2: src = W2; dst = D2; break;
        default: src = W3; dst = D3; break;
    }
    __shared__ float tile[32][33];
    int bx = blockIdx.x, by = blockIdx.y;
    int tx = threadIdx.x & 31, ty = threadIdx.x >> 5;
    for (int i = 0; i < 4; i++)
        tile[ty + 8*i][tx] = src[(size_t)(by*32 + ty + 8*i) * 1024 + bx*32 + tx];
    __syncthreads();
    for (int i = 0; i < 4; i++)
        dst[(size_t)(bx*32 + ty + 8*i) * 1024 + by*32 + tx] = f2bf(tile[tx][ty + 8*i]);
}

// ---------------- QKV projection GEMM, 256x256 tile, counted-vmcnt phase
// schedule (T3+T4+T5). 8 waves (2M x 4N), per-wave output 128x64, BK=64,
// LDS 128KB, granule-XOR swizzle (proven 0-conflict).
// ROUND-13 FIX vs r12: phases 1..3 issue their A-fragment ds_reads in the
// INTER-BARRIER GAP (before the entry barrier), per the m201 template order
// {ds_read -> stage -> barrier -> MFMA -> barrier} -- the ~120cy LDS latency
// overlaps the barrier convergence instead of sitting on the MFMA critical
// path. Legal: buffer `cur` is fully visible since this K-tile's phase-0
// vmcnt+barrier; the phase-0 asm memory clobber fences upward motion.
// Phase 0 keeps reads after its barrier (availability point).
__global__ __launch_bounds__(512) void gemm256_kernel(
    const unsigned short* __restrict__ A,    // hsb [4096][1024]
    const unsigned short* __restrict__ BT,   // WT  [3072][1024]
    unsigned short* __restrict__ C1,         // qkb [4096][2048]
    unsigned short* __restrict__ Vt){        // [2][1024][2048]
    constexpr int K = 1024, NK = 16;
    __shared__ __align__(16) unsigned short As[2][256 * 64];
    __shared__ __align__(16) unsigned short Bs[2][256 * 64];
    const int t = threadIdx.x;
    const int wv = t >> 6, lane = t & 63, quad = lane >> 4, l16 = lane & 15;
    const int wm = wv >> 2, wn = wv & 3;                 // 2M x 4N
    const size_t row0 = (size_t)blockIdx.y * 256, col0 = (size_t)blockIdx.x * 256;

    const int srow8 = lane >> 3;
    const int gg = (lane & 7) ^ srow8;                   // fetch-side granule remap
    const unsigned short* gA = A  + (row0 + wv * 8 + srow8) * (size_t)K + gg * 8;
    const unsigned short* gB = BT + (col0 + wv * 8 + srow8) * (size_t)K + gg * 8;

    f32x4 acc[8][4] = {};

    auto stage2 = [&](int kt, int p, int buf){
        gload16(gA + (size_t)(p * 64) * K + kt * 64, &As[buf][(p * 64 + wv * 8) * 64]);
        gload16(gB + (size_t)(p * 64) * K + kt * 64, &Bs[buf][(p * 64 + wv * 8) * 64]);
    };
    auto readA = [&](bf16x8 afr[2][2], int cur, int qd){
        for (int ks = 0; ks < 2; ks++)
            for (int i = 0; i < 2; i++)
                afr[ks][i] = *(const bf16x8*)&As[cur][(wm * 128 + qd * 32 + i * 16 + l16) * 64 + (((ks * 4 + quad) ^ (l16 & 7)) * 8)];
    };
    auto mfma16 = [&](bf16x8 afr[2][2], bf16x8 bfr[2][4], int qd){
        __builtin_amdgcn_s_setprio(1);
        for (int ks = 0; ks < 2; ks++)
            for (int i = 0; i < 2; i++)
                for (int j = 0; j < 4; j++)
                    acc[qd * 2 + i][j] = __builtin_amdgcn_mfma_f32_16x16x32_bf16(
                        afr[ks][i], bfr[ks][j], acc[qd * 2 + i][j], 0, 0, 0);
        __builtin_amdgcn_s_setprio(0);
    };
    // prologue: tile 0 fully staged into buf 0 (8 loads/wave)
    for (int p = 0; p < 4; p++) stage2(0, p, 0);

    for (int kt = 0; kt < NK; kt++) {
        const int cur = kt & 1;
        bf16x8 bfr[2][4];   // B fragments: read once at phase 0, live all 4 phases
        bf16x8 afr[2][2];
        // ---- phase 0: availability point for buffer `cur` ----
        if (kt + 1 < NK) {
            stage2(kt + 1, 0, cur ^ 1);
            // tile kt's 8 loads must land; the 2 just-issued stay in flight
            asm volatile("s_waitcnt vmcnt(2)" ::: "memory");
        } else {
            asm volatile("s_waitcnt vmcnt(0)" ::: "memory");
        }
        __builtin_amdgcn_s_barrier();
        for (int ks = 0; ks < 2; ks++)
            for (int j = 0; j < 4; j++)
                bfr[ks][j] = *(const bf16x8*)&Bs[cur][(wn * 64 + j * 16 + l16) * 64 + (((ks * 4 + quad) ^ (l16 & 7)) * 8)];
        readA(afr, cur, 0);
        mfma16(afr, bfr, 0);
        __builtin_amdgcn_s_barrier();
        // ---- phases 1..3: ds_read hoisted into the inter-barrier gap ----
#pragma unroll
        for (int qd = 1; qd < 4; qd++) {
            readA(afr, cur, qd);                      // overlaps barrier convergence
            if (kt + 1 < NK) stage2(kt + 1, qd, cur ^ 1);
            __builtin_amdgcn_s_barrier();             // entry
            mfma16(afr, bfr, qd);
            __builtin_amdgcn_s_barrier();             // exit
        }
    }
    // epilogue: C/D layout col = lane&15, row = quad*4 + reg
    const bool isV = (col0 >= 2048);
    const float qs = (col0 < 1024) ? LOG2E : 1.0f;
    for (int i = 0; i < 8; i++)
        for (int j = 0; j < 4; j++) {
            size_t r0 = row0 + wm * 128 + i * 16 + quad * 4;
            size_t c  = col0 + wn * 64 + j * 16 + l16;
            if (!isV) {
                for (int r = 0; r < 4; r++)
                    C1[(r0 + r) * 2048 + c] = f2bf(acc[i][j][r] * qs);
            } else {
                // V: rows r0..r0+3 are 4 consecutive s -> one 8B store, transposed
                size_t bb = r0 >> 11, s = r0 & 2047;
                ushort4 o;
                o.x = f2bf(acc[i][j][0]); o.y = f2bf(acc[i][j][1]);
                o.z = f2bf(acc[i][j][2]); o.w = f2bf(acc[i][j][3]);
                *(ushort4*)(Vt + ((bb << 10) + (c - 2048)) * 2048 + s) = o;
            }
        }
}

// ---------------- output-projection GEMM (MODE 2): BK=64, single-buffer,
// A = NORMALIZED context computed on the fly from two bf16 partials and row
// sums RS (combine fused into A-staging, 1-step register prefetch); fp32 out.
template<int MODE, int BM>
__global__ __launch_bounds__(256) void gemm_bt_kernel(const unsigned short* __restrict__ A,
                                                      const unsigned short* __restrict__ BT,
                                                      float* __restrict__ C0,
                                                      const float* __restrict__ RS,
                                                      int Kdim, int ldc){
    constexpr int IT = BM / 32;     // m-tiles per wave
    __shared__ __align__(16) unsigned short As[BM * 64];
    __shared__ __align__(16) unsigned short Bs[128 * 64];
    const int t = threadIdx.x;
    const int wave = t >> 6, lane = t & 63;
    const int quad = lane >> 4, l16 = lane & 15;
    const int wm = (wave >> 1) * (BM / 2), wn = (wave & 1) * 64;
    const size_t row0 = (size_t)blockIdx.y * BM, col0 = (size_t)blockIdx.x * 128;

    const int srow8 = lane >> 3;                 // 0..7: row within the wave's 8-row group
    const int gg = (lane & 7) ^ srow8;           // fetch-side granule remap
    const unsigned short* gB = BT + (col0 + wave * 8 + srow8) * (size_t)Kdim + gg * 8;

    f32x4 acc[IT][4] = {};

    bf16x8 pa0[2], pa1[2];
    float ra[2], rb[2];
    auto issueA2 = [&](int kt){
        for (int p = 0; p < 2; p++) {
            size_t row = row0 + p * 32 + wave * 8 + srow8;
            const unsigned short* pp = A + row * 1024 + kt + gg * 8;
            pa0[p] = *(const bf16x8*)pp;
            pa1[p] = *(const bf16x8*)(pp + (size_t)4096 * 1024);
            int head = kt >> 6;
            ra[p] = RS[row * 16 + head];
            rb[p] = RS[(4096 + row) * 16 + head];
        }
    };
    issueA2(0);
    for (int kt = 0; kt < Kdim; kt += 64) {
        for (int p = 0; p < 2; p++) {
            float inv = 1.f / (ra[p] + rb[p]);
            unsigned int u4[4];
            for (int e = 0; e < 4; e++) {
                float x0 = (float)pa0[p][2 * e]     + (float)pa1[p][2 * e];
                float x1 = (float)pa0[p][2 * e + 1] + (float)pa1[p][2 * e + 1];
                u4[e] = pkbf(x0 * inv, x1 * inv);
            }
            bf16x8 pv;
            __builtin_memcpy(&pv, u4, 16);
            *(bf16x8*)&As[(p * 32 + wave * 8) * 64 + lane * 8] = pv;
        }
        for (int p = 0; p < 4; p++)
            gload16(gB + (size_t)(p * 32) * Kdim + kt, &Bs[(p * 32 + wave * 8) * 64]);
        if (kt + 64 < Kdim)
            issueA2(kt + 64);   // in flight across the MFMA phase + 2 barriers
        __syncthreads();
        bf16x8 a[2][IT], b[2][4];
        for (int ks = 0; ks < 2; ks++) {
            for (int i = 0; i < IT; i++)
                a[ks][i] = *(const bf16x8*)(&As[(wm + i*16 + l16) * 64 + (((ks*4 + quad) ^ (l16 & 7)) * 8)]);
            for (int j = 0; j < 4; j++)
                b[ks][j] = *(const bf16x8*)(&Bs[(wn + j*16 + l16) * 64 + (((ks*4 + quad) ^ (l16 & 7)) * 8)]);
        }
        for (int ks = 0; ks < 2; ks++)
            for (int i = 0; i < IT; i++)
                for (int j = 0; j < 4; j++)
                    acc[i][j] = __builtin_amdgcn_mfma_f32_16x16x32_bf16(a[ks][i], b[ks][j], acc[i][j], 0, 0, 0);
        __syncthreads();
    }
    for (int i = 0; i < IT; i++)
        for (int j = 0; j < 4; j++) {
            size_t r0 = row0 + wm + i*16 + quad*4;
            size_t c  = col0 + wn + j*16 + l16;
            for (int r = 0; r < 4; r++)
                C0[(r0 + r) * ldc + c] = acc[i][j][r];
        }
}

// ---------------- MFMA flash attention v18 (best measured: 48.4 us):
// split-S x2, 8 waves x 32q, chunked XCD swizzle, double-buffered K/V
// prefetch, bias as MFMA C-init via 16B float4 LDS table, nb-outer pipelined
// QK^T+exp2, in-register P via permlane32/16_swap, row sums via ones-row MFMA.
__global__ __launch_bounds__(512, 4) void flash18_kernel(
    const unsigned short* __restrict__ qkb,   // [4096][2048] bf16: Q | K
    const unsigned short* __restrict__ vt,    // [2][1024][2048] bf16 V^T
    const float* __restrict__ biasT,          // pre-scaled (x-16)*log2e
    unsigned short* __restrict__ ctxpb,       // [2][4096][1024] bf16 unnormalized
    float* __restrict__ rsbuf)                // [2][4096][16]  fp32 row sums
{
    const int lin  = blockIdx.x;               // 0..511
    const int logi = (lin & 7) * 64 + (lin >> 3);
    const int qt = logi & 7, h = (logi >> 3) & 15;
    const int zz = logi >> 7;                  // 0..3
    const int b = zz >> 1, ck = zz & 1;
    const int kt0 = ck << 10;                  // 1024 j per chunk
    const int t = threadIdx.x;
    const int w = t >> 6, lane = t & 63, quad = lane >> 4, l16 = lane & 15;
    const int q0 = qt * 256;

    __shared__ __align__(16) unsigned short Ks[2][64 * 64];   // [token j][dim], swizzled
    __shared__ __align__(16) unsigned short Vs[2][64 * 64];   // [dim d][token], swizzled
    __shared__ __align__(16) float bias4_b[1280 * 4];         // redundant x4: entry u = biasT[u..u+3]

    {
        const float* bsrc = biasT + h * NB_DELTA + (kt0 - q0 + 1792);   // 2047-255 = 1792
        for (int u = t; u < 1276; u += 512) {
            float a0 = bsrc[u], a1 = bsrc[u + 1], a2 = bsrc[u + 2], a3 = bsrc[u + 3];
            float4* d = (float4*)&bias4_b[u * 4];
            *d = float4{a0, a1, a2, a3};
        }
    }
    const int srow8 = lane >> 3;
    const int gg = (lane & 7) ^ srow8;           // fetch-side granule remap
    const int swz = (l16 & 7) * 8;
    const unsigned short* kbase = qkb + (size_t)(b * S_LEN + w * 8 + srow8) * 2048 + 1024 + h * 64 + gg * 8;
    const unsigned short* vbase = vt + (size_t)(b * 1024 + h * 64 + w * 8 + srow8) * 2048 + gg * 8;
    gload16(kbase + (size_t)kt0 * 2048, &Ks[0][(w * 8) * 64]);
    gload16(vbase + kt0,                &Vs[0][(w * 8) * 64]);

    bf16x8 qb[2][2];   // [ks][nt]; wave owns q rows q0 + w*32 + nt*16 + l16
    {
        const unsigned short* qbase =
            qkb + (size_t)(b * S_LEN + q0 + w * 32 + l16) * 2048 + h * 64 + quad * 8;
        for (int nt = 0; nt < 2; nt++)
            for (int ks = 0; ks < 2; ks++)
                qb[ks][nt] = *(const bf16x8*)(qbase + (size_t)nt * 16 * 2048 + ks * 32);
    }
    __syncthreads();   // bias4_b + first K/V tile ready

    bf16x8 onesA = {};
    if (l16 == 0) {
        const __bf16 one = (__bf16)1.0f;
        for (int e = 0; e < 8; e++) onesA[e] = one;
    }

    f32x4 ctx[4][2] = {};    // ctx^T: [d-tile nd][n-tile nt]
    f32x4 rsacc[2] = {};     // row 0 (quad==0, reg 0) = running row sum per q
    const int ib0 = 255 + quad * 4 - w * 32 - l16;   // + i*64 - nt*16 + nb*16 + r

    int cur = 0;
    for (int i = 0; i < 16; i++) {
        if (i < 15) {
            int ktn = kt0 + (i + 1) * 64;
            gload16(kbase + (size_t)ktn * 2048, &Ks[cur ^ 1][(w * 8) * 64]);
            gload16(vbase + ktn,                &Vs[cur ^ 1][(w * 8) * 64]);
        }
        const int ibt = ib0 + i * 64;
        uint2 pk[2][4];   // [nt][nb]
        for (int nb = 0; nb < 4; nb++) {
            const int krow = (nb * 16 + l16) * 64;
            bf16x8 ka0 = *(const bf16x8*)&Ks[cur][krow + ((quad * 8) ^ swz)];
            bf16x8 ka1 = *(const bf16x8*)&Ks[cur][krow + (((4 + quad) * 8) ^ swz)];
            f32x4 st0 = *(const f32x4*)&bias4_b[(ibt + nb * 16) * 4];        // nt=0
            f32x4 st1 = *(const f32x4*)&bias4_b[(ibt - 16 + nb * 16) * 4];   // nt=1
            st0 = __builtin_amdgcn_mfma_f32_16x16x32_bf16(ka0, qb[0][0], st0, 0, 0, 0);
            st0 = __builtin_amdgcn_mfma_f32_16x16x32_bf16(ka1, qb[1][0], st0, 0, 0, 0);
            st1 = __builtin_amdgcn_mfma_f32_16x16x32_bf16(ka0, qb[0][1], st1, 0, 0, 0);
            st1 = __builtin_amdgcn_mfma_f32_16x16x32_bf16(ka1, qb[1][1], st1, 0, 0, 0);
            pk[0][nb].x = pkbf(fexp2(st0[0]), fexp2(st0[1]));
            pk[0][nb].y = pkbf(fexp2(st0[2]), fexp2(st0[3]));
            pk[1][nb].x = pkbf(fexp2(st1[0]), fexp2(st1[1]));
            pk[1][nb].y = pkbf(fexp2(st1[2]), fexp2(st1[3]));
        }
        __builtin_amdgcn_s_setprio(1);
        for (int ks = 0; ks < 2; ks++) {
            bf16x8 pbf[2];
            for (int nt = 0; nt < 2; nt++) {
                uint2 x0 = pk[nt][2 * ks], x1 = pk[nt][2 * ks + 1];
                auto sA = __builtin_amdgcn_permlane32_swap(x0.x, x1.x, false, false);
                auto sB = __builtin_amdgcn_permlane16_swap(sA[0], sA[1], false, false);
                auto sC = __builtin_amdgcn_permlane32_swap(x0.y, x1.y, false, false);
                auto sD = __builtin_amdgcn_permlane16_swap(sC[0], sC[1], false, false);
                unsigned int u4[4] = {sB[0], sD[0], sB[1], sD[1]};
                __builtin_memcpy(&pbf[nt], u4, 16);
            }
            rsacc[0] = __builtin_amdgcn_mfma_f32_16x16x32_bf16(onesA, pbf[0], rsacc[0], 0, 0, 0);
            rsacc[1] = __builtin_amdgcn_mfma_f32_16x16x32_bf16(onesA, pbf[1], rsacc[1], 0, 0, 0);
            for (int nd = 0; nd < 4; nd++) {
                bf16x8 va = *(const bf16x8*)&Vs[cur][(nd * 16 + l16) * 64 + (((ks * 4 + quad) * 8) ^ swz)];
                ctx[nd][0] = __builtin_amdgcn_mfma_f32_16x16x32_bf16(va, pbf[0], ctx[nd][0], 0, 0, 0);
                ctx[nd][1] = __builtin_amdgcn_mfma_f32_16x16x32_bf16(va, pbf[1], ctx[nd][1], 0, 0, 0);
            }
        }
        __builtin_amdgcn_s_setprio(0);
        __syncthreads();   // drains prefetch vmcnt (already landed) + guards buffer swap
        cur ^= 1;
    }
    unsigned short* cp = ctxpb + (size_t)ck * 4096 * 1024;
    for (int nt = 0; nt < 2; nt++) {
        int row = b * S_LEN + q0 + w * 32 + nt * 16 + l16;
        if (quad == 0) rsbuf[((size_t)ck * 4096 + row) * 16 + h] = rsacc[nt][0];
        for (int nd = 0; nd < 4; nd++) {
            uint2 pk2;
            pk2.x = pkbf(ctx[nd][nt][0], ctx[nd][nt][1]);
            pk2.y = pkbf(ctx[nd][nt][2], ctx[nd][nt][3]);
            *(uint2*)&cp[(size_t)row * 1024 + h * 64 + nd * 16 + quad * 4] = pk2;
        }
    }
}

extern "C" void kernel_launch(void* const* d_in, const int* in_sizes, int n_in,
                              void* d_out, int out_size, void* d_ws, size_t ws_size,
                              hipStream_t stream) {
    const float* hs       = (const float*)d_in[0];
    const float* Wq       = (const float*)d_in[1];
    const float* Wk       = (const float*)d_in[2];
    const float* Wv       = (const float*)d_in[3];
    const float* Wo       = (const float*)d_in[4];
    const float* rel_bias = (const float*)d_in[5];
    float* out = (float*)d_out;

    char* ws = (char*)d_ws;
    float* biasT          = (float*)ws;           ws += 262144;      // 16*4095*4 (+pad)
    unsigned short* hsb   = (unsigned short*)ws;  ws += 8388608;     // 4096x1024 bf16
    unsigned short* WT    = (unsigned short*)ws;  ws += 6291456;     // [Wq^T|Wk^T|Wv^T] 3072x1024
    unsigned short* WoT   = (unsigned short*)ws;  ws += 2097152;     // 1024x1024 bf16
    unsigned short* qkb   = (unsigned short*)ws;  ws += 16777216;    // 4096x2048 bf16 (Q|K)
    unsigned short* Vtg   = (unsigned short*)ws;  ws += 8388608;     // 2048x2048 bf16
    unsigned short* ctxpb = (unsigned short*)ws;  ws += 16777216;    // 2 x 4096x1024 bf16
    float* rsbuf          = (float*)ws;                              // 2 x 4096x16 fp32

    // prep v1 (measured best)
    prep_kernel<<<dim3(32, 32, 5), 256, 0, stream>>>(
        hs, hsb, Wq, Wk, Wv, Wo,
        WT, WT + 1024 * 1024, WT + 2 * 1024 * 1024, WoT, rel_bias, biasT);

    // Q|K|V projection: 256x256 counted-vmcnt phase schedule, 192 blocks x 512 thr
    gemm256_kernel<<<dim3(12, 16), 512, 0, stream>>>(hsb, WT, qkb, Vtg);
    // attention, split-S x2, 256-q blocks of 8 waves x 32q: 512 blocks = 2/CU, XCD-swizzled
    flash18_kernel<<<dim3(512), 512, 0, stream>>>(qkb, Vtg, biasT, ctxpb, rsbuf);
    // output projection -> fp32, with combine fused into PREFETCHED A-staging
    gemm_bt_kernel<2, 64><<<dim3(8, 64), 256, 0, stream>>>(ctxpb, WoT, out, rsbuf, 1024, 1024);
}

// Round 14
// 194.753 us; speedup vs baseline: 1.2267x; 1.2267x over previous
//
#include <hip/hip_runtime.h>
#include <hip/hip_bf16.h>
#include <stdint.h>

#define S_LEN 2048
#define NH 16
#define NB_DELTA (2*S_LEN-1)   // 4095
#define LOG2E 1.4426950408889634f

typedef __attribute__((ext_vector_type(8))) __bf16 bf16x8;
typedef __attribute__((ext_vector_type(4))) float f32x4;

__device__ __forceinline__ unsigned short f2bf(float f){   // RNE
    union { float f; unsigned int u; } v; v.f = f;
    unsigned int u = v.u;
    return (unsigned short)((u + 0x7FFFu + ((u >> 16) & 1u)) >> 16);
}
__device__ __forceinline__ float bf2f(unsigned short u){
    union { unsigned int u; float f; } v; v.u = ((unsigned int)u) << 16;
    return v.f;
}
__device__ __forceinline__ unsigned int pkbf(float a, float b){   // HW packed cvt (RNE)
    __hip_bfloat162 h = __float22bfloat162_rn(float2{a, b});
    unsigned int u;
    __builtin_memcpy(&u, &h, 4);
    return u;
}
#if __has_builtin(__builtin_amdgcn_exp2f)
__device__ __forceinline__ float fexp2(float x){ return __builtin_amdgcn_exp2f(x); }
#else
__device__ __forceinline__ float fexp2(float x){ return __expf(x * 0.69314718056f); }
#endif

// async global->LDS, 16B per lane; LDS dest = wave-uniform base + lane*16
__device__ __forceinline__ void gload16(const void* g, void* l){
    __builtin_amdgcn_global_load_lds(
        (const __attribute__((address_space(1))) void*)(uintptr_t)g,
        (__attribute__((address_space(3))) void*)(uintptr_t)l, 16, 0, 0);
}

// ---------------- fused prep (v1 -- measured best): z<4 -> transpose+cast W[z];
// z==4 -> hs cast + bias table. biasT is PRE-SCALED: (bias - 16) * log2e.
__global__ __launch_bounds__(256) void prep_kernel(
    const float* __restrict__ hs, unsigned short* __restrict__ hsb,
    const float* __restrict__ W0, const float* __restrict__ W1,
    const float* __restrict__ W2, const float* __restrict__ W3,
    unsigned short* __restrict__ D0, unsigned short* __restrict__ D1,
    unsigned short* __restrict__ D2, unsigned short* __restrict__ D3,
    const float* __restrict__ rel_bias, float* __restrict__ biasT){
    if (blockIdx.z == 4) {
        int bi = blockIdx.y * 32 + blockIdx.x;   // 0..1023
        for (int it = 0; it < 4; it++) {
            int i = bi * 4096 + it * 1024 + threadIdx.x * 4;
            float4 f = *(const float4*)(hs + i);
            ushort4 o;
            o.x = f2bf(f.x); o.y = f2bf(f.y); o.z = f2bf(f.z); o.w = f2bf(f.w);
            *(ushort4*)(hsb + i) = o;
        }
        if (bi < 16) {
            int t = bi * 256 + threadIdx.x;
            if (t < NB_DELTA) {
                int delta = t - (S_LEN - 1);          // j - i
                int bucket = (delta > 0) ? 16 : 0;
                int a = delta < 0 ? -delta : delta;
                int b;
                if (a < 8) b = a;
                else {
                    int bl = 33 - __builtin_clz(a * a);   // 8 + floor(2*log2(a/8)), exact
                    b = bl < 15 ? bl : 15;
                }
                bucket += b;
                for (int h = 0; h < NH; h++)
                    biasT[h * NB_DELTA + t] = (rel_bias[bucket * NH + h] - 16.f) * LOG2E;
            }
        }
        return;
    }
    const float* src; unsigned short* dst;
    switch (blockIdx.z) {
        case 0: src = W0; dst = D0; break;
        case 1: src = W1; dst = D1; break;
        case 2: src = W2; dst = D2; break;
        default: src = W3; dst = D3; break;
    }
    __shared__ float tile[32][33];
    int bx = blockIdx.x, by = blockIdx.y;
    int tx = threadIdx.x & 31, ty = threadIdx.x >> 5;
    for (int i = 0; i < 4; i++)
        tile[ty + 8*i][tx] = src[(size_t)(by*32 + ty + 8*i) * 1024 + bx*32 + tx];
    __syncthreads();
    for (int i = 0; i < 4; i++)
        dst[(size_t)(bx*32 + ty + 8*i) * 1024 + by*32 + tx] = f2bf(tile[tx][ty + 8*i]);
}

// ---------------- bf16 MFMA GEMM, BK=64, async staging, XOR-granule-swizzled LDS.
// MODE 1: 2-PHASE DOUBLE-BUFFERED staging (r11, best-measured config) + NEW:
//         chunked XCD swizzle -- each XCD owns a 12x16 rectangle of (bx,by)
//         tiles, balancing per-XCD L2 traffic (~3MB B + 2MB A vs 0.75+8 with
//         the default round-robin); more loads hit L2 (~200cy) instead of HBM
//         (~900cy) on the barrier-exposed latency path. bf16 out (Q pre-scaled
//         log2e, Q|K stride 2048); cols>=2048 (V) written transposed into Vt.
// MODE 2: single-buffer (proven): A = normalized context from two bf16
//         partials + row sums RS (combine fused, 1-step register prefetch),
//         fp32 out; chunked XCD swizzle (by-range per XCD).
template<int MODE, int BM>
__global__ __launch_bounds__(256) void gemm_bt_kernel(const unsigned short* __restrict__ A,
                                                      const unsigned short* __restrict__ BT,
                                                      float* __restrict__ C0,
                                                      unsigned short* __restrict__ C1,
                                                      unsigned short* __restrict__ Vt,
                                                      const float* __restrict__ RS,
                                                      int Kdim, int ldc){
    constexpr int IT = BM / 32;     // m-tiles per wave
    constexpr int NBUF = (MODE == 2) ? 1 : 2;
    __shared__ __align__(16) unsigned short As[NBUF][BM * 64];
    __shared__ __align__(16) unsigned short Bs[NBUF][128 * 64];
    const int t = threadIdx.x;
    const int wave = t >> 6, lane = t & 63;
    const int quad = lane >> 4, l16 = lane & 15;
    const int wm = (wave >> 1) * (BM / 2), wn = (wave & 1) * 64;

    // chunked XCD swizzle (bijective; physical lin%8 ~ XCD)
    int bx = blockIdx.x, by = blockIdx.y;
    if (MODE == 1) {            // grid (24,64): XCD c -> bx in [(c&1)*12,+12), by in [(c>>1)*16,+16)
        int lin = by * 24 + bx;
        int c = lin & 7, w2 = lin >> 3;           // w2 in [0,192)
        bx = (c & 1) * 12 + w2 % 12;
        by = (c >> 1) * 16 + w2 / 12;
    } else {                    // grid (8,64): XCD c -> all bx, by in [c*8,+8)
        int lin = by * 8 + bx;
        int c = lin & 7, w2 = lin >> 3;           // w2 in [0,64)
        bx = w2 & 7;
        by = c * 8 + (w2 >> 3);
    }
    const size_t row0 = (size_t)by * BM, col0 = (size_t)bx * 128;

    const int srow8 = lane >> 3;                 // 0..7: row within the wave's 8-row group
    const int gg = (lane & 7) ^ srow8;           // fetch-side granule remap
    const unsigned short* gA = A  + (row0 + wave * 8 + srow8) * (size_t)Kdim + gg * 8;
    const unsigned short* gB = BT + (col0 + wave * 8 + srow8) * (size_t)Kdim + gg * 8;

    f32x4 acc[IT][4] = {};

    if constexpr (MODE != 2) {
        // ---- 2-phase double-buffered K-loop (r11) ----
        const int nk = Kdim >> 6;
        for (int p = 0; p < BM / 32; p++)
            gload16(gA + (size_t)(p * 32) * Kdim, &As[0][(p * 32 + wave * 8) * 64]);
        for (int p = 0; p < 4; p++)
            gload16(gB + (size_t)(p * 32) * Kdim, &Bs[0][(p * 32 + wave * 8) * 64]);
        __syncthreads();   // drains prologue staging
        for (int ki = 0; ki < nk; ki++) {
            const int cur = ki & 1;
            if (ki + 1 < nk) {   // prefetch next tile into the other buffer
                const int kt = (ki + 1) << 6;
                for (int p = 0; p < BM / 32; p++)
                    gload16(gA + (size_t)(p * 32) * Kdim + kt, &As[cur ^ 1][(p * 32 + wave * 8) * 64]);
                for (int p = 0; p < 4; p++)
                    gload16(gB + (size_t)(p * 32) * Kdim + kt, &Bs[cur ^ 1][(p * 32 + wave * 8) * 64]);
            }
            bf16x8 a[2][IT], b[2][4];
            for (int ks = 0; ks < 2; ks++) {
                for (int i = 0; i < IT; i++)
                    a[ks][i] = *(const bf16x8*)(&As[cur][(wm + i*16 + l16) * 64 + (((ks*4 + quad) ^ (l16 & 7)) * 8)]);
                for (int j = 0; j < 4; j++)
                    b[ks][j] = *(const bf16x8*)(&Bs[cur][(wn + j*16 + l16) * 64 + (((ks*4 + quad) ^ (l16 & 7)) * 8)]);
            }
            for (int ks = 0; ks < 2; ks++)
                for (int i = 0; i < IT; i++)
                    for (int j = 0; j < 4; j++)
                        acc[i][j] = __builtin_amdgcn_mfma_f32_16x16x32_bf16(a[ks][i], b[ks][j], acc[i][j], 0, 0, 0);
            __syncthreads();   // drains prefetch (mostly landed) + guards buffer swap
        }
    } else {
        // ---- MODE 2: single-buffer with register-prefetched normalized A ----
        bf16x8 pa0[2], pa1[2];
        float ra[2], rb[2];
        auto issueA2 = [&](int kt){
            for (int p = 0; p < 2; p++) {
                size_t row = row0 + p * 32 + wave * 8 + srow8;
                const unsigned short* pp = A + row * 1024 + kt + gg * 8;
                pa0[p] = *(const bf16x8*)pp;
                pa1[p] = *(const bf16x8*)(pp + (size_t)4096 * 1024);
                int head = kt >> 6;
                ra[p] = RS[row * 16 + head];
                rb[p] = RS[(4096 + row) * 16 + head];
            }
        };
        issueA2(0);
        for (int kt = 0; kt < Kdim; kt += 64) {
            for (int p = 0; p < 2; p++) {
                float inv = 1.f / (ra[p] + rb[p]);
                unsigned int u4[4];
                for (int e = 0; e < 4; e++) {
                    float x0 = (float)pa0[p][2 * e]     + (float)pa1[p][2 * e];
                    float x1 = (float)pa0[p][2 * e + 1] + (float)pa1[p][2 * e + 1];
                    u4[e] = pkbf(x0 * inv, x1 * inv);
                }
                bf16x8 pv;
                __builtin_memcpy(&pv, u4, 16);
                *(bf16x8*)&As[0][(p * 32 + wave * 8) * 64 + lane * 8] = pv;
            }
            for (int p = 0; p < 4; p++)
                gload16(gB + (size_t)(p * 32) * Kdim + kt, &Bs[0][(p * 32 + wave * 8) * 64]);
            if (kt + 64 < Kdim)
                issueA2(kt + 64);   // in flight across the MFMA phase + 2 barriers
            __syncthreads();
            bf16x8 a[2][IT], b[2][4];
            for (int ks = 0; ks < 2; ks++) {
                for (int i = 0; i < IT; i++)
                    a[ks][i] = *(const bf16x8*)(&As[0][(wm + i*16 + l16) * 64 + (((ks*4 + quad) ^ (l16 & 7)) * 8)]);
                for (int j = 0; j < 4; j++)
                    b[ks][j] = *(const bf16x8*)(&Bs[0][(wn + j*16 + l16) * 64 + (((ks*4 + quad) ^ (l16 & 7)) * 8)]);
            }
            for (int ks = 0; ks < 2; ks++)
                for (int i = 0; i < IT; i++)
                    for (int j = 0; j < 4; j++)
                        acc[i][j] = __builtin_amdgcn_mfma_f32_16x16x32_bf16(a[ks][i], b[ks][j], acc[i][j], 0, 0, 0);
            __syncthreads();
        }
    }
    // C/D layout: col = lane&15, row = quad*4 + reg
    for (int i = 0; i < IT; i++)
        for (int j = 0; j < 4; j++) {
            size_t r0 = row0 + wm + i*16 + quad*4;
            size_t c  = col0 + wn + j*16 + l16;
            if (MODE == 0 || MODE == 2) {
                for (int r = 0; r < 4; r++)
                    C0[(r0 + r) * ldc + c] = acc[i][j][r];
            } else if (c < 2048) {
                float qs = (c < 1024) ? LOG2E : 1.0f;   // pre-scale Q for exp2 softmax
                for (int r = 0; r < 4; r++)
                    C1[(r0 + r) * ldc + c] = f2bf(acc[i][j][r] * qs);
            } else {
                // V block: write transposed. rows r0..r0+3 are 4 consecutive s -> one 8B store.
                size_t bb = r0 >> 11, s = r0 & 2047;
                ushort4 o;
                o.x = f2bf(acc[i][j][0]); o.y = f2bf(acc[i][j][1]);
                o.z = f2bf(acc[i][j][2]); o.w = f2bf(acc[i][j][3]);
                *(ushort4*)(Vt + ((bb << 10) + (c - 2048)) * 2048 + s) = o;
            }
        }
}

// ---------------- MFMA flash attention v18 (best measured: 48.4 us):
// split-S x2, 8 waves x 32q, chunked XCD swizzle, double-buffered K/V
// prefetch, bias as MFMA C-init via 16B float4 LDS table, nb-outer pipelined
// QK^T+exp2, in-register P via permlane32/16_swap, row sums via ones-row MFMA.
__global__ __launch_bounds__(512, 4) void flash18_kernel(
    const unsigned short* __restrict__ qkb,   // [4096][2048] bf16: Q | K
    const unsigned short* __restrict__ vt,    // [2][1024][2048] bf16 V^T
    const float* __restrict__ biasT,          // pre-scaled (x-16)*log2e
    unsigned short* __restrict__ ctxpb,       // [2][4096][1024] bf16 unnormalized
    float* __restrict__ rsbuf)                // [2][4096][16]  fp32 row sums
{
    const int lin  = blockIdx.x;               // 0..511
    const int logi = (lin & 7) * 64 + (lin >> 3);
    const int qt = logi & 7, h = (logi >> 3) & 15;
    const int zz = logi >> 7;                  // 0..3
    const int b = zz >> 1, ck = zz & 1;
    const int kt0 = ck << 10;                  // 1024 j per chunk
    const int t = threadIdx.x;
    const int w = t >> 6, lane = t & 63, quad = lane >> 4, l16 = lane & 15;
    const int q0 = qt * 256;

    __shared__ __align__(16) unsigned short Ks[2][64 * 64];   // [token j][dim], swizzled
    __shared__ __align__(16) unsigned short Vs[2][64 * 64];   // [dim d][token], swizzled
    __shared__ __align__(16) float bias4_b[1280 * 4];         // redundant x4: entry u = biasT[u..u+3]

    {
        const float* bsrc = biasT + h * NB_DELTA + (kt0 - q0 + 1792);   // 2047-255 = 1792
        for (int u = t; u < 1276; u += 512) {
            float a0 = bsrc[u], a1 = bsrc[u + 1], a2 = bsrc[u + 2], a3 = bsrc[u + 3];
            float4* d = (float4*)&bias4_b[u * 4];
            *d = float4{a0, a1, a2, a3};
        }
    }
    const int srow8 = lane >> 3;
    const int gg = (lane & 7) ^ srow8;           // fetch-side granule remap
    const int swz = (l16 & 7) * 8;
    const unsigned short* kbase = qkb + (size_t)(b * S_LEN + w * 8 + srow8) * 2048 + 1024 + h * 64 + gg * 8;
    const unsigned short* vbase = vt + (size_t)(b * 1024 + h * 64 + w * 8 + srow8) * 2048 + gg * 8;
    gload16(kbase + (size_t)kt0 * 2048, &Ks[0][(w * 8) * 64]);
    gload16(vbase + kt0,                &Vs[0][(w * 8) * 64]);

    bf16x8 qb[2][2];   // [ks][nt]; wave owns q rows q0 + w*32 + nt*16 + l16
    {
        const unsigned short* qbase =
            qkb + (size_t)(b * S_LEN + q0 + w * 32 + l16) * 2048 + h * 64 + quad * 8;
        for (int nt = 0; nt < 2; nt++)
            for (int ks = 0; ks < 2; ks++)
                qb[ks][nt] = *(const bf16x8*)(qbase + (size_t)nt * 16 * 2048 + ks * 32);
    }
    __syncthreads();   // bias4_b + first K/V tile ready

    bf16x8 onesA = {};
    if (l16 == 0) {
        const __bf16 one = (__bf16)1.0f;
        for (int e = 0; e < 8; e++) onesA[e] = one;
    }

    f32x4 ctx[4][2] = {};    // ctx^T: [d-tile nd][n-tile nt]
    f32x4 rsacc[2] = {};     // row 0 (quad==0, reg 0) = running row sum per q
    const int ib0 = 255 + quad * 4 - w * 32 - l16;   // + i*64 - nt*16 + nb*16 + r

    int cur = 0;
    for (int i = 0; i < 16; i++) {
        if (i < 15) {
            int ktn = kt0 + (i + 1) * 64;
            gload16(kbase + (size_t)ktn * 2048, &Ks[cur ^ 1][(w * 8) * 64]);
            gload16(vbase + ktn,                &Vs[cur ^ 1][(w * 8) * 64]);
        }
        const int ibt = ib0 + i * 64;
        uint2 pk[2][4];   // [nt][nb]
        for (int nb = 0; nb < 4; nb++) {
            const int krow = (nb * 16 + l16) * 64;
            bf16x8 ka0 = *(const bf16x8*)&Ks[cur][krow + ((quad * 8) ^ swz)];
            bf16x8 ka1 = *(const bf16x8*)&Ks[cur][krow + (((4 + quad) * 8) ^ swz)];
            f32x4 st0 = *(const f32x4*)&bias4_b[(ibt + nb * 16) * 4];        // nt=0
            f32x4 st1 = *(const f32x4*)&bias4_b[(ibt - 16 + nb * 16) * 4];   // nt=1
            st0 = __builtin_amdgcn_mfma_f32_16x16x32_bf16(ka0, qb[0][0], st0, 0, 0, 0);
            st0 = __builtin_amdgcn_mfma_f32_16x16x32_bf16(ka1, qb[1][0], st0, 0, 0, 0);
            st1 = __builtin_amdgcn_mfma_f32_16x16x32_bf16(ka0, qb[0][1], st1, 0, 0, 0);
            st1 = __builtin_amdgcn_mfma_f32_16x16x32_bf16(ka1, qb[1][1], st1, 0, 0, 0);
            pk[0][nb].x = pkbf(fexp2(st0[0]), fexp2(st0[1]));
            pk[0][nb].y = pkbf(fexp2(st0[2]), fexp2(st0[3]));
            pk[1][nb].x = pkbf(fexp2(st1[0]), fexp2(st1[1]));
            pk[1][nb].y = pkbf(fexp2(st1[2]), fexp2(st1[3]));
        }
        __builtin_amdgcn_s_setprio(1);
        for (int ks = 0; ks < 2; ks++) {
            bf16x8 pbf[2];
            for (int nt = 0; nt < 2; nt++) {
                uint2 x0 = pk[nt][2 * ks], x1 = pk[nt][2 * ks + 1];
                auto sA = __builtin_amdgcn_permlane32_swap(x0.x, x1.x, false, false);
                auto sB = __builtin_amdgcn_permlane16_swap(sA[0], sA[1], false, false);
                auto sC = __builtin_amdgcn_permlane32_swap(x0.y, x1.y, false, false);
                auto sD = __builtin_amdgcn_permlane16_swap(sC[0], sC[1], false, false);
                unsigned int u4[4] = {sB[0], sD[0], sB[1], sD[1]};
                __builtin_memcpy(&pbf[nt], u4, 16);
            }
            rsacc[0] = __builtin_amdgcn_mfma_f32_16x16x32_bf16(onesA, pbf[0], rsacc[0], 0, 0, 0);
            rsacc[1] = __builtin_amdgcn_mfma_f32_16x16x32_bf16(onesA, pbf[1], rsacc[1], 0, 0, 0);
            for (int nd = 0; nd < 4; nd++) {
                bf16x8 va = *(const bf16x8*)&Vs[cur][(nd * 16 + l16) * 64 + (((ks * 4 + quad) * 8) ^ swz)];
                ctx[nd][0] = __builtin_amdgcn_mfma_f32_16x16x32_bf16(va, pbf[0], ctx[nd][0], 0, 0, 0);
                ctx[nd][1] = __builtin_amdgcn_mfma_f32_16x16x32_bf16(va, pbf[1], ctx[nd][1], 0, 0, 0);
            }
        }
        __builtin_amdgcn_s_setprio(0);
        __syncthreads();   // drains prefetch vmcnt (already landed) + guards buffer swap
        cur ^= 1;
    }
    unsigned short* cp = ctxpb + (size_t)ck * 4096 * 1024;
    for (int nt = 0; nt < 2; nt++) {
        int row = b * S_LEN + q0 + w * 32 + nt * 16 + l16;
        if (quad == 0) rsbuf[((size_t)ck * 4096 + row) * 16 + h] = rsacc[nt][0];
        for (int nd = 0; nd < 4; nd++) {
            uint2 pk2;
            pk2.x = pkbf(ctx[nd][nt][0], ctx[nd][nt][1]);
            pk2.y = pkbf(ctx[nd][nt][2], ctx[nd][nt][3]);
            *(uint2*)&cp[(size_t)row * 1024 + h * 64 + nd * 16 + quad * 4] = pk2;
        }
    }
}

extern "C" void kernel_launch(void* const* d_in, const int* in_sizes, int n_in,
                              void* d_out, int out_size, void* d_ws, size_t ws_size,
                              hipStream_t stream) {
    const float* hs       = (const float*)d_in[0];
    const float* Wq       = (const float*)d_in[1];
    const float* Wk       = (const float*)d_in[2];
    const float* Wv       = (const float*)d_in[3];
    const float* Wo       = (const float*)d_in[4];
    const float* rel_bias = (const float*)d_in[5];
    float* out = (float*)d_out;

    char* ws = (char*)d_ws;
    float* biasT          = (float*)ws;           ws += 262144;      // 16*4095*4 (+pad)
    unsigned short* hsb   = (unsigned short*)ws;  ws += 8388608;     // 4096x1024 bf16
    unsigned short* WT    = (unsigned short*)ws;  ws += 6291456;     // [Wq^T|Wk^T|Wv^T] 3072x1024
    unsigned short* WoT   = (unsigned short*)ws;  ws += 2097152;     // 1024x1024 bf16
    unsigned short* qkb   = (unsigned short*)ws;  ws += 16777216;    // 4096x2048 bf16 (Q|K)
    unsigned short* Vtg   = (unsigned short*)ws;  ws += 8388608;     // 2048x2048 bf16
    unsigned short* ctxpb = (unsigned short*)ws;  ws += 16777216;    // 2 x 4096x1024 bf16
    float* rsbuf          = (float*)ws;                              // 2 x 4096x16 fp32

    // prep v1 (measured best)
    prep_kernel<<<dim3(32, 32, 5), 256, 0, stream>>>(
        hs, hsb, Wq, Wk, Wv, Wo,
        WT, WT + 1024 * 1024, WT + 2 * 1024 * 1024, WoT, rel_bias, biasT);

    // Q|K|V projection, BM=64, 2-phase double-buffered + chunked XCD swizzle
    gemm_bt_kernel<1, 64><<<dim3(24, 64), 256, 0, stream>>>(hsb, WT, nullptr, qkb, Vtg, nullptr, 1024, 2048);
    // attention, split-S x2, 256-q blocks of 8 waves x 32q: 512 blocks = 2/CU, XCD-swizzled
    flash18_kernel<<<dim3(512), 512, 0, stream>>>(qkb, Vtg, biasT, ctxpb, rsbuf);
    // output projection -> fp32, with combine fused into PREFETCHED A-staging + XCD swizzle
    gemm_bt_kernel<2, 64><<<dim3(8, 64), 256, 0, stream>>>(ctxpb, WoT, out, nullptr, nullptr, rsbuf, 1024, 1024);
}

// Round 15
// 185.484 us; speedup vs baseline: 1.2880x; 1.0500x over previous
//
#include <hip/hip_runtime.h>
#include <hip/hip_bf16.h>
#include <stdint.h>

#define S_LEN 2048
#define NH 16
#define NB_DELTA (2*S_LEN-1)   // 4095
#define LOG2E 1.4426950408889634f

typedef __attribute__((ext_vector_type(8))) __bf16 bf16x8;
typedef __attribute__((ext_vector_type(4))) float f32x4;

__device__ __forceinline__ unsigned short f2bf(float f){   // RNE
    union { float f; unsigned int u; } v; v.f = f;
    unsigned int u = v.u;
    return (unsigned short)((u + 0x7FFFu + ((u >> 16) & 1u)) >> 16);
}
__device__ __forceinline__ float bf2f(unsigned short u){
    union { unsigned int u; float f; } v; v.u = ((unsigned int)u) << 16;
    return v.f;
}
__device__ __forceinline__ unsigned int pkbf(float a, float b){   // HW packed cvt (RNE)
    __hip_bfloat162 h = __float22bfloat162_rn(float2{a, b});
    unsigned int u;
    __builtin_memcpy(&u, &h, 4);
    return u;
}
#if __has_builtin(__builtin_amdgcn_exp2f)
__device__ __forceinline__ float fexp2(float x){ return __builtin_amdgcn_exp2f(x); }
#else
__device__ __forceinline__ float fexp2(float x){ return __expf(x * 0.69314718056f); }
#endif

// async global->LDS, 16B per lane; LDS dest = wave-uniform base + lane*16
__device__ __forceinline__ void gload16(const void* g, void* l){
    __builtin_amdgcn_global_load_lds(
        (const __attribute__((address_space(1))) void*)(uintptr_t)g,
        (__attribute__((address_space(3))) void*)(uintptr_t)l, 16, 0, 0);
}

// ---------------- fused prep (v1 -- measured best): z<4 -> transpose+cast W[z];
// z==4 -> hs cast + bias table. biasT is PRE-SCALED: (bias - 16) * log2e.
__global__ __launch_bounds__(256) void prep_kernel(
    const float* __restrict__ hs, unsigned short* __restrict__ hsb,
    const float* __restrict__ W0, const float* __restrict__ W1,
    const float* __restrict__ W2, const float* __restrict__ W3,
    unsigned short* __restrict__ D0, unsigned short* __restrict__ D1,
    unsigned short* __restrict__ D2, unsigned short* __restrict__ D3,
    const float* __restrict__ rel_bias, float* __restrict__ biasT){
    if (blockIdx.z == 4) {
        int bi = blockIdx.y * 32 + blockIdx.x;   // 0..1023
        for (int it = 0; it < 4; it++) {
            int i = bi * 4096 + it * 1024 + threadIdx.x * 4;
            float4 f = *(const float4*)(hs + i);
            ushort4 o;
            o.x = f2bf(f.x); o.y = f2bf(f.y); o.z = f2bf(f.z); o.w = f2bf(f.w);
            *(ushort4*)(hsb + i) = o;
        }
        if (bi < 16) {
            int t = bi * 256 + threadIdx.x;
            if (t < NB_DELTA) {
                int delta = t - (S_LEN - 1);          // j - i
                int bucket = (delta > 0) ? 16 : 0;
                int a = delta < 0 ? -delta : delta;
                int b;
                if (a < 8) b = a;
                else {
                    int bl = 33 - __builtin_clz(a * a);   // 8 + floor(2*log2(a/8)), exact
                    b = bl < 15 ? bl : 15;
                }
                bucket += b;
                for (int h = 0; h < NH; h++)
                    biasT[h * NB_DELTA + t] = (rel_bias[bucket * NH + h] - 16.f) * LOG2E;
            }
        }
        return;
    }
    const float* src; unsigned short* dst;
    switch (blockIdx.z) {
        case 0: src = W0; dst = D0; break;
        case 1: src = W1; dst = D1; break;
        case 2: src = W2; dst = D2; break;
        default: src = W3; dst = D3; break;
    }
    __shared__ float tile[32][33];
    int bx = blockIdx.x, by = blockIdx.y;
    int tx = threadIdx.x & 31, ty = threadIdx.x >> 5;
    for (int i = 0; i < 4; i++)
        tile[ty + 8*i][tx] = src[(size_t)(by*32 + ty + 8*i) * 1024 + bx*32 + tx];
    __syncthreads();
    for (int i = 0; i < 4; i++)
        dst[(size_t)(bx*32 + ty + 8*i) * 1024 + by*32 + tx] = f2bf(tile[tx][ty + 8*i]);
}

// ---------------- bf16 MFMA GEMM, BK=64, async staging, XOR-granule-swizzled LDS.
// MODE 1: 2-PHASE DOUBLE-BUFFERED staging (prefetch tile k+1 before computing
//         tile k; ONE barrier per K-step). bf16 into C1 for cols<2048 (Q
//         pre-scaled by log2e; Q|K packed at stride 2048); cols>=2048 (V)
//         written TRANSPOSED into Vt[b*1024+v][s].
// MODE 2: single-buffer path (proven): A = normalized context from two bf16
//         partials + row sums RS (combine fused, 1-step register prefetch),
//         fp32 into C0.
template<int MODE, int BM>
__global__ __launch_bounds__(256) void gemm_bt_kernel(const unsigned short* __restrict__ A,
                                                      const unsigned short* __restrict__ BT,
                                                      float* __restrict__ C0,
                                                      unsigned short* __restrict__ C1,
                                                      unsigned short* __restrict__ Vt,
                                                      const float* __restrict__ RS,
                                                      int Kdim, int ldc){
    constexpr int IT = BM / 32;     // m-tiles per wave
    constexpr int NBUF = (MODE == 2) ? 1 : 2;
    __shared__ __align__(16) unsigned short As[NBUF][BM * 64];
    __shared__ __align__(16) unsigned short Bs[NBUF][128 * 64];
    const int t = threadIdx.x;
    const int wave = t >> 6, lane = t & 63;
    const int quad = lane >> 4, l16 = lane & 15;
    const int wm = (wave >> 1) * (BM / 2), wn = (wave & 1) * 64;
    const size_t row0 = (size_t)blockIdx.y * BM, col0 = (size_t)blockIdx.x * 128;

    const int srow8 = lane >> 3;                 // 0..7: row within the wave's 8-row group
    const int gg = (lane & 7) ^ srow8;           // fetch-side granule remap
    const unsigned short* gA = A  + (row0 + wave * 8 + srow8) * (size_t)Kdim + gg * 8;
    const unsigned short* gB = BT + (col0 + wave * 8 + srow8) * (size_t)Kdim + gg * 8;

    f32x4 acc[IT][4] = {};

    if constexpr (MODE != 2) {
        // ---- 2-phase double-buffered K-loop ----
        const int nk = Kdim >> 6;
        for (int p = 0; p < BM / 32; p++)
            gload16(gA + (size_t)(p * 32) * Kdim, &As[0][(p * 32 + wave * 8) * 64]);
        for (int p = 0; p < 4; p++)
            gload16(gB + (size_t)(p * 32) * Kdim, &Bs[0][(p * 32 + wave * 8) * 64]);
        __syncthreads();   // drains prologue staging
        for (int ki = 0; ki < nk; ki++) {
            const int cur = ki & 1;
            if (ki + 1 < nk) {   // prefetch next tile into the other buffer
                const int kt = (ki + 1) << 6;
                for (int p = 0; p < BM / 32; p++)
                    gload16(gA + (size_t)(p * 32) * Kdim + kt, &As[cur ^ 1][(p * 32 + wave * 8) * 64]);
                for (int p = 0; p < 4; p++)
                    gload16(gB + (size_t)(p * 32) * Kdim + kt, &Bs[cur ^ 1][(p * 32 + wave * 8) * 64]);
            }
            bf16x8 a[2][IT], b[2][4];
            for (int ks = 0; ks < 2; ks++) {
                for (int i = 0; i < IT; i++)
                    a[ks][i] = *(const bf16x8*)(&As[cur][(wm + i*16 + l16) * 64 + (((ks*4 + quad) ^ (l16 & 7)) * 8)]);
                for (int j = 0; j < 4; j++)
                    b[ks][j] = *(const bf16x8*)(&Bs[cur][(wn + j*16 + l16) * 64 + (((ks*4 + quad) ^ (l16 & 7)) * 8)]);
            }
            for (int ks = 0; ks < 2; ks++)
                for (int i = 0; i < IT; i++)
                    for (int j = 0; j < 4; j++)
                        acc[i][j] = __builtin_amdgcn_mfma_f32_16x16x32_bf16(a[ks][i], b[ks][j], acc[i][j], 0, 0, 0);
            __syncthreads();   // drains prefetch (mostly landed) + guards buffer swap
        }
    } else {
        // ---- MODE 2: single-buffer with register-prefetched normalized A ----
        bf16x8 pa0[2], pa1[2];
        float ra[2], rb[2];
        auto issueA2 = [&](int kt){
            for (int p = 0; p < 2; p++) {
                size_t row = row0 + p * 32 + wave * 8 + srow8;
                const unsigned short* pp = A + row * 1024 + kt + gg * 8;
                pa0[p] = *(const bf16x8*)pp;
                pa1[p] = *(const bf16x8*)(pp + (size_t)4096 * 1024);
                int head = kt >> 6;
                ra[p] = RS[row * 16 + head];
                rb[p] = RS[(4096 + row) * 16 + head];
            }
        };
        issueA2(0);
        for (int kt = 0; kt < Kdim; kt += 64) {
            for (int p = 0; p < 2; p++) {
                float inv = 1.f / (ra[p] + rb[p]);
                unsigned int u4[4];
                for (int e = 0; e < 4; e++) {
                    float x0 = (float)pa0[p][2 * e]     + (float)pa1[p][2 * e];
                    float x1 = (float)pa0[p][2 * e + 1] + (float)pa1[p][2 * e + 1];
                    u4[e] = pkbf(x0 * inv, x1 * inv);
                }
                bf16x8 pv;
                __builtin_memcpy(&pv, u4, 16);
                *(bf16x8*)&As[0][(p * 32 + wave * 8) * 64 + lane * 8] = pv;
            }
            for (int p = 0; p < 4; p++)
                gload16(gB + (size_t)(p * 32) * Kdim + kt, &Bs[0][(p * 32 + wave * 8) * 64]);
            if (kt + 64 < Kdim)
                issueA2(kt + 64);   // in flight across the MFMA phase + 2 barriers
            __syncthreads();
            bf16x8 a[2][IT], b[2][4];
            for (int ks = 0; ks < 2; ks++) {
                for (int i = 0; i < IT; i++)
                    a[ks][i] = *(const bf16x8*)(&As[0][(wm + i*16 + l16) * 64 + (((ks*4 + quad) ^ (l16 & 7)) * 8)]);
                for (int j = 0; j < 4; j++)
                    b[ks][j] = *(const bf16x8*)(&Bs[0][(wn + j*16 + l16) * 64 + (((ks*4 + quad) ^ (l16 & 7)) * 8)]);
            }
            for (int ks = 0; ks < 2; ks++)
                for (int i = 0; i < IT; i++)
                    for (int j = 0; j < 4; j++)
                        acc[i][j] = __builtin_amdgcn_mfma_f32_16x16x32_bf16(a[ks][i], b[ks][j], acc[i][j], 0, 0, 0);
            __syncthreads();
        }
    }
    // C/D layout: col = lane&15, row = quad*4 + reg
    for (int i = 0; i < IT; i++)
        for (int j = 0; j < 4; j++) {
            size_t r0 = row0 + wm + i*16 + quad*4;
            size_t c  = col0 + wn + j*16 + l16;
            if (MODE == 0 || MODE == 2) {
                for (int r = 0; r < 4; r++)
                    C0[(r0 + r) * ldc + c] = acc[i][j][r];
            } else if (c < 2048) {
                float qs = (c < 1024) ? LOG2E : 1.0f;   // pre-scale Q for exp2 softmax
                for (int r = 0; r < 4; r++)
                    C1[(r0 + r) * ldc + c] = f2bf(acc[i][j][r] * qs);
            } else {
                // V block: write transposed. rows r0..r0+3 are 4 consecutive s -> one 8B store.
                size_t bb = r0 >> 11, s = r0 & 2047;
                ushort4 o;
                o.x = f2bf(acc[i][j][0]); o.y = f2bf(acc[i][j][1]);
                o.z = f2bf(acc[i][j][2]); o.w = f2bf(acc[i][j][3]);
                *(ushort4*)(Vt + ((bb << 10) + (c - 2048)) * 2048 + s) = o;
            }
        }
}

// ---------------- MFMA flash attention v18 (best measured: 48.4 us):
// split-S x2, 8 waves x 32q, chunked XCD swizzle, double-buffered K/V
// prefetch, bias as MFMA C-init via 16B float4 LDS table, nb-outer pipelined
// QK^T+exp2, in-register P via permlane32/16_swap, row sums via ones-row MFMA.
__global__ __launch_bounds__(512, 4) void flash18_kernel(
    const unsigned short* __restrict__ qkb,   // [4096][2048] bf16: Q | K
    const unsigned short* __restrict__ vt,    // [2][1024][2048] bf16 V^T
    const float* __restrict__ biasT,          // pre-scaled (x-16)*log2e
    unsigned short* __restrict__ ctxpb,       // [2][4096][1024] bf16 unnormalized
    float* __restrict__ rsbuf)                // [2][4096][16]  fp32 row sums
{
    const int lin  = blockIdx.x;               // 0..511
    const int logi = (lin & 7) * 64 + (lin >> 3);
    const int qt = logi & 7, h = (logi >> 3) & 15;
    const int zz = logi >> 7;                  // 0..3
    const int b = zz >> 1, ck = zz & 1;
    const int kt0 = ck << 10;                  // 1024 j per chunk
    const int t = threadIdx.x;
    const int w = t >> 6, lane = t & 63, quad = lane >> 4, l16 = lane & 15;
    const int q0 = qt * 256;

    __shared__ __align__(16) unsigned short Ks[2][64 * 64];   // [token j][dim], swizzled
    __shared__ __align__(16) unsigned short Vs[2][64 * 64];   // [dim d][token], swizzled
    __shared__ __align__(16) float bias4_b[1280 * 4];         // redundant x4: entry u = biasT[u..u+3]

    {
        const float* bsrc = biasT + h * NB_DELTA + (kt0 - q0 + 1792);   // 2047-255 = 1792
        for (int u = t; u < 1276; u += 512) {
            float a0 = bsrc[u], a1 = bsrc[u + 1], a2 = bsrc[u + 2], a3 = bsrc[u + 3];
            float4* d = (float4*)&bias4_b[u * 4];
            *d = float4{a0, a1, a2, a3};
        }
    }
    const int srow8 = lane >> 3;
    const int gg = (lane & 7) ^ srow8;           // fetch-side granule remap
    const int swz = (l16 & 7) * 8;
    const unsigned short* kbase = qkb + (size_t)(b * S_LEN + w * 8 + srow8) * 2048 + 1024 + h * 64 + gg * 8;
    const unsigned short* vbase = vt + (size_t)(b * 1024 + h * 64 + w * 8 + srow8) * 2048 + gg * 8;
    gload16(kbase + (size_t)kt0 * 2048, &Ks[0][(w * 8) * 64]);
    gload16(vbase + kt0,                &Vs[0][(w * 8) * 64]);

    bf16x8 qb[2][2];   // [ks][nt]; wave owns q rows q0 + w*32 + nt*16 + l16
    {
        const unsigned short* qbase =
            qkb + (size_t)(b * S_LEN + q0 + w * 32 + l16) * 2048 + h * 64 + quad * 8;
        for (int nt = 0; nt < 2; nt++)
            for (int ks = 0; ks < 2; ks++)
                qb[ks][nt] = *(const bf16x8*)(qbase + (size_t)nt * 16 * 2048 + ks * 32);
    }
    __syncthreads();   // bias4_b + first K/V tile ready

    bf16x8 onesA = {};
    if (l16 == 0) {
        const __bf16 one = (__bf16)1.0f;
        for (int e = 0; e < 8; e++) onesA[e] = one;
    }

    f32x4 ctx[4][2] = {};    // ctx^T: [d-tile nd][n-tile nt]
    f32x4 rsacc[2] = {};     // row 0 (quad==0, reg 0) = running row sum per q
    const int ib0 = 255 + quad * 4 - w * 32 - l16;   // + i*64 - nt*16 + nb*16 + r

    int cur = 0;
    for (int i = 0; i < 16; i++) {
        if (i < 15) {
            int ktn = kt0 + (i + 1) * 64;
            gload16(kbase + (size_t)ktn * 2048, &Ks[cur ^ 1][(w * 8) * 64]);
            gload16(vbase + ktn,                &Vs[cur ^ 1][(w * 8) * 64]);
        }
        const int ibt = ib0 + i * 64;
        uint2 pk[2][4];   // [nt][nb]
        for (int nb = 0; nb < 4; nb++) {
            const int krow = (nb * 16 + l16) * 64;
            bf16x8 ka0 = *(const bf16x8*)&Ks[cur][krow + ((quad * 8) ^ swz)];
            bf16x8 ka1 = *(const bf16x8*)&Ks[cur][krow + (((4 + quad) * 8) ^ swz)];
            f32x4 st0 = *(const f32x4*)&bias4_b[(ibt + nb * 16) * 4];        // nt=0
            f32x4 st1 = *(const f32x4*)&bias4_b[(ibt - 16 + nb * 16) * 4];   // nt=1
            st0 = __builtin_amdgcn_mfma_f32_16x16x32_bf16(ka0, qb[0][0], st0, 0, 0, 0);
            st0 = __builtin_amdgcn_mfma_f32_16x16x32_bf16(ka1, qb[1][0], st0, 0, 0, 0);
            st1 = __builtin_amdgcn_mfma_f32_16x16x32_bf16(ka0, qb[0][1], st1, 0, 0, 0);
            st1 = __builtin_amdgcn_mfma_f32_16x16x32_bf16(ka1, qb[1][1], st1, 0, 0, 0);
            pk[0][nb].x = pkbf(fexp2(st0[0]), fexp2(st0[1]));
            pk[0][nb].y = pkbf(fexp2(st0[2]), fexp2(st0[3]));
            pk[1][nb].x = pkbf(fexp2(st1[0]), fexp2(st1[1]));
            pk[1][nb].y = pkbf(fexp2(st1[2]), fexp2(st1[3]));
        }
        __builtin_amdgcn_s_setprio(1);
        for (int ks = 0; ks < 2; ks++) {
            bf16x8 pbf[2];
            for (int nt = 0; nt < 2; nt++) {
                uint2 x0 = pk[nt][2 * ks], x1 = pk[nt][2 * ks + 1];
                auto sA = __builtin_amdgcn_permlane32_swap(x0.x, x1.x, false, false);
                auto sB = __builtin_amdgcn_permlane16_swap(sA[0], sA[1], false, false);
                auto sC = __builtin_amdgcn_permlane32_swap(x0.y, x1.y, false, false);
                auto sD = __builtin_amdgcn_permlane16_swap(sC[0], sC[1], false, false);
                unsigned int u4[4] = {sB[0], sD[0], sB[1], sD[1]};
                __builtin_memcpy(&pbf[nt], u4, 16);
            }
            rsacc[0] = __builtin_amdgcn_mfma_f32_16x16x32_bf16(onesA, pbf[0], rsacc[0], 0, 0, 0);
            rsacc[1] = __builtin_amdgcn_mfma_f32_16x16x32_bf16(onesA, pbf[1], rsacc[1], 0, 0, 0);
            for (int nd = 0; nd < 4; nd++) {
                bf16x8 va = *(const bf16x8*)&Vs[cur][(nd * 16 + l16) * 64 + (((ks * 4 + quad) * 8) ^ swz)];
                ctx[nd][0] = __builtin_amdgcn_mfma_f32_16x16x32_bf16(va, pbf[0], ctx[nd][0], 0, 0, 0);
                ctx[nd][1] = __builtin_amdgcn_mfma_f32_16x16x32_bf16(va, pbf[1], ctx[nd][1], 0, 0, 0);
            }
        }
        __builtin_amdgcn_s_setprio(0);
        __syncthreads();   // drains prefetch vmcnt (already landed) + guards buffer swap
        cur ^= 1;
    }
    unsigned short* cp = ctxpb + (size_t)ck * 4096 * 1024;
    for (int nt = 0; nt < 2; nt++) {
        int row = b * S_LEN + q0 + w * 32 + nt * 16 + l16;
        if (quad == 0) rsbuf[((size_t)ck * 4096 + row) * 16 + h] = rsacc[nt][0];
        for (int nd = 0; nd < 4; nd++) {
            uint2 pk2;
            pk2.x = pkbf(ctx[nd][nt][0], ctx[nd][nt][1]);
            pk2.y = pkbf(ctx[nd][nt][2], ctx[nd][nt][3]);
            *(uint2*)&cp[(size_t)row * 1024 + h * 64 + nd * 16 + quad * 4] = pk2;
        }
    }
}

extern "C" void kernel_launch(void* const* d_in, const int* in_sizes, int n_in,
                              void* d_out, int out_size, void* d_ws, size_t ws_size,
                              hipStream_t stream) {
    const float* hs       = (const float*)d_in[0];
    const float* Wq       = (const float*)d_in[1];
    const float* Wk       = (const float*)d_in[2];
    const float* Wv       = (const float*)d_in[3];
    const float* Wo       = (const float*)d_in[4];
    const float* rel_bias = (const float*)d_in[5];
    float* out = (float*)d_out;

    char* ws = (char*)d_ws;
    float* biasT          = (float*)ws;           ws += 262144;      // 16*4095*4 (+pad)
    unsigned short* hsb   = (unsigned short*)ws;  ws += 8388608;     // 4096x1024 bf16
    unsigned short* WT    = (unsigned short*)ws;  ws += 6291456;     // [Wq^T|Wk^T|Wv^T] 3072x1024
    unsigned short* WoT   = (unsigned short*)ws;  ws += 2097152;     // 1024x1024 bf16
    unsigned short* qkb   = (unsigned short*)ws;  ws += 16777216;    // 4096x2048 bf16 (Q|K)
    unsigned short* Vtg   = (unsigned short*)ws;  ws += 8388608;     // 2048x2048 bf16
    unsigned short* ctxpb = (unsigned short*)ws;  ws += 16777216;    // 2 x 4096x1024 bf16
    float* rsbuf          = (float*)ws;                              // 2 x 4096x16 fp32

    // prep v1 (measured best)
    prep_kernel<<<dim3(32, 32, 5), 256, 0, stream>>>(
        hs, hsb, Wq, Wk, Wv, Wo,
        WT, WT + 1024 * 1024, WT + 2 * 1024 * 1024, WoT, rel_bias, biasT);

    // Q|K|V projection, BM=64, 2-phase double-buffered (1536 blocks, 48KB LDS = 3/CU)
    gemm_bt_kernel<1, 64><<<dim3(24, 64), 256, 0, stream>>>(hsb, WT, nullptr, qkb, Vtg, nullptr, 1024, 2048);
    // attention, split-S x2, 256-q blocks of 8 waves x 32q: 512 blocks = 2/CU, XCD-swizzled
    flash18_kernel<<<dim3(512), 512, 0, stream>>>(qkb, Vtg, biasT, ctxpb, rsbuf);
    // output projection -> fp32, with combine fused into PREFETCHED A-staging
    gemm_bt_kernel<2, 64><<<dim3(8, 64), 256, 0, stream>>>(ctxpb, WoT, out, nullptr, nullptr, rsbuf, 1024, 1024);
}